// Round 15
// baseline (502.381 us; speedup 1.0000x reference)
//
#include <hip/hip_runtime.h>

// ---------------------------------------------------------------------------
// EdgeModel: out = LayerNorm(LReLU(LReLU(LReLU(X@W1+b1)@W2+b2)@W3+b3))
// X = concat[src, dest, edge_attr, u[batch]]  (E=400000, 512 features)
// R15: BARRIER-FREE LAYER 1. B-frag (x) layout is directly global-loadable:
//      lane l reads x[edge n*16+(l&15)][k + (l>>4)*8 ..+8] = 2 dwordx4 + 4
//      cvt_pk. The 4 waves re-read the same 8KB/kk window -> L1$ serves the
//      redundancy (HBM ~1x). Deletes xs, all L1 staging + ALL L1 barriers
//      (waves drift; setprio arbitrates). h2 -> dedicated hs2. Barriers
//      10 -> 3. Base otherwise = R13 (294us: 4-bit swizzle, fused LN,
//      operand swap, W warm-ups). R14 lesson: acc[4][4] => 2 waves/SIMD
//      or spill -- no launch_bounds cap.
// ---------------------------------------------------------------------------

typedef short bf16x8 __attribute__((ext_vector_type(8)));   // 8 bf16 (guide §3)
typedef float f32x4 __attribute__((ext_vector_type(4)));
typedef unsigned int u32;
typedef unsigned int u32x2 __attribute__((ext_vector_type(2)));

__device__ __forceinline__ unsigned short f2bf(float f) {  // RNE f32->bf16
    union { float f; unsigned u; } v; v.f = f;
    return (unsigned short)((v.u + 0x7fffu + ((v.u >> 16) & 1u)) >> 16);
}
__device__ __forceinline__ u32 cvtpk(float lo, float hi) { // d={bf16(hi),bf16(lo)}
    u32 r;
    asm("v_cvt_pk_bf16_f32 %0, %1, %2" : "=v"(r) : "v"(lo), "v"(hi));
    return r;
}
__device__ __forceinline__ bf16x8 pack8(f32x4 a, f32x4 b) { // 8 f32 -> bf16x8
    union { u32 q[4]; bf16x8 v; } r;
    r.q[0] = cvtpk(a.x, a.y); r.q[1] = cvtpk(a.z, a.w);
    r.q[2] = cvtpk(b.x, b.y); r.q[3] = cvtpk(b.z, b.w);
    return r.v;
}
__device__ __forceinline__ float lrelu(float v) { return v >= 0.f ? v : 0.01f * v; }

// ---------------------------------------------------------------------------
// Pack W (K x N, row-major f32) into bf16 MFMA fragment order (A operand):
// frag(fk,fn): lane l, elem j  ->  W[fk*32 + (l>>4)*8 + j][fn*16 + (l&15)]
// offset(elems) = ((fk*nfn + fn)*64 + l)*8 + j
// ---------------------------------------------------------------------------
__global__ void prep_pack(const float* __restrict__ W1, const float* __restrict__ W2,
                          const float* __restrict__ W3, unsigned short* __restrict__ P) {
    int idx = blockIdx.x * 256 + threadIdx.x;
    const float* W; int N, base;
    if (idx < 131072)      { W = W1; N = 256; base = 0; }
    else if (idx < 196608) { W = W2; N = 256; base = 131072; }
    else if (idx < 229376) { W = W3; N = 128; base = 196608; }
    else return;
    int t = idx - base;
    int j = t & 7, l = (t >> 3) & 63, f = t >> 9;
    int nfn = N >> 4;
    int fk = f / nfn, fn = f - fk * nfn;
    int k = fk * 32 + ((l >> 4) << 3) + j;
    int c = fn * 16 + (l & 15);
    P[idx] = f2bf(W[k * N + c]);
}

// ---------------------------------------------------------------------------
// Main fused kernel. Block = 256 threads (4 waves, feat-split), M_TILE = 64.
// Wave: 64 feats x 64 edges. acc[4][4] (feat-frag x edge-frag), D[feat][edge].
// LDS: hs 32KB (h1) + hs2 32KB (h2) + lnp 2KB = 66KB -> 2 blocks/CU.
// ---------------------------------------------------------------------------
template <bool EXACT>
__global__ __launch_bounds__(256) void edge_mlp(
    const float* __restrict__ src, const float* __restrict__ dst,
    const float* __restrict__ ea,  const float* __restrict__ u,
    const int* __restrict__ batch, const unsigned short* __restrict__ Wp,
    const float* __restrict__ b1,  const float* __restrict__ b2,
    const float* __restrict__ b3,  const float* __restrict__ gamma,
    const float* __restrict__ beta, float* __restrict__ out, int E)
{
    __shared__ __align__(16) unsigned char hs[64 * 512];    // 32KB (h1)
    __shared__ __align__(16) unsigned char hs2[64 * 512];   // 32KB (h2)
    __shared__ __align__(16) float lnp[64][4][2];           // 2KB partials

    const int tid  = threadIdx.x;
    const int lane = tid & 63;
    const int wn   = tid >> 6;          // wave 0..3 = feature quarter
    const int l15  = lane & 15;
    const int lhi  = lane >> 4;         // 0..3
    const int m0   = blockIdx.x * 64;

    // Per-lane edge rows for the 4 edge-frags + their batch gathers
    int erow[4], gb4[4];
    #pragma unroll
    for (int n = 0; n < 4; ++n) {
        int rg = m0 + n * 16 + l15;
        if (!EXACT) rg = rg < E ? rg : E - 1;
        erow[n] = rg;
        gb4[n]  = batch[rg];
    }

    const unsigned short* W1p = Wp;
    const unsigned short* W2p = Wp + 131072;
    const unsigned short* W3p = Wp + 196608;

    const f32x4 zero4 = {0.f, 0.f, 0.f, 0.f};
    f32x4 acc[4][4];                    // [feat-frag][edge-frag]
    #pragma unroll
    for (int m = 0; m < 4; ++m)
        #pragma unroll
        for (int n = 0; n < 4; ++n) acc[m][n] = zero4;

    // ===================== layer 1 (K=512) — BARRIER-FREE ===================
    // Per seg (src/dst/ea/u[batch]): lane-direct global loads feed B-frags.
    #pragma unroll
    for (int seg = 0; seg < 4; ++seg) {
        const float* rowp[4];
        #pragma unroll
        for (int n = 0; n < 4; ++n) {
            const float* bp = (seg == 0) ? src : (seg == 1) ? dst
                             : (seg == 2) ? ea : u;
            const int r = (seg == 3) ? gb4[n] : erow[n];
            rowp[n] = bp + (size_t)r * 128 + lhi * 8;
        }
        #pragma unroll
        for (int h = 0; h < 2; ++h) {   // two K=64 halves; W-frags upfront
            bf16x8 wA[4], wB[4];
            const int fkA = seg * 4 + h * 2, fkB = fkA + 1;
            #pragma unroll
            for (int m = 0; m < 4; ++m) {
                int fm = wn * 4 + m;
                wA[m] = *reinterpret_cast<const bf16x8*>(
                    W1p + (((fkA * 16 + fm) << 6) + lane) * 8);
                wB[m] = *reinterpret_cast<const bf16x8*>(
                    W1p + (((fkB * 16 + fm) << 6) + lane) * 8);
            }
            #pragma unroll
            for (int kk = 0; kk < 2; ++kk) {
                const int ko = h * 64 + kk * 32;   // k offset within segment
                bf16x8 xf[4];
                #pragma unroll
                for (int n = 0; n < 4; ++n) {
                    f32x4 a = *reinterpret_cast<const f32x4*>(rowp[n] + ko);
                    f32x4 b = *reinterpret_cast<const f32x4*>(rowp[n] + ko + 4);
                    xf[n] = pack8(a, b);
                }
                __builtin_amdgcn_s_setprio(1);
                #pragma unroll
                for (int m = 0; m < 4; ++m)
                    #pragma unroll
                    for (int n = 0; n < 4; ++n)
                        acc[m][n] = __builtin_amdgcn_mfma_f32_16x16x32_bf16(
                            kk == 0 ? wA[m] : wB[m], xf[n], acc[m][n], 0, 0, 0);
                __builtin_amdgcn_s_setprio(0);
            }
        }
    }

    // W2 kk=0 warm-up (hides under h1 epilogue + barrier)
    bf16x8 wc4[4];
    #pragma unroll
    for (int m = 0; m < 4; ++m)
        wc4[m] = *reinterpret_cast<const bf16x8*>(
            W2p + (((wn * 4 + m) << 6) + lane) * 8);

    // h1 = LReLU(acc + b1) -> hs. Lane holds 4 consecutive feats of one edge.
    #pragma unroll
    for (int m = 0; m < 4; ++m) {
        int f = wn * 64 + m * 16 + lhi * 4;
        f32x4 bb = *reinterpret_cast<const f32x4*>(b1 + f);
        #pragma unroll
        for (int n = 0; n < 4; ++n) {
            int e = n * 16 + l15;
            f32x4 v = acc[m][n];
            u32x2 h;
            h.x = cvtpk(lrelu(v[0] + bb.x), lrelu(v[1] + bb.y));
            h.y = cvtpk(lrelu(v[2] + bb.z), lrelu(v[3] + bb.w));
            *reinterpret_cast<u32x2*>(
                &hs[e * 512 + ((f * 2) ^ ((e & 15) << 4))]) = h;
        }
    }
    __syncthreads();   // barrier 1: h1 visible

    // ============================ layer 2 (K=256) ===========================
    #pragma unroll
    for (int m = 0; m < 4; ++m)
        #pragma unroll
        for (int n = 0; n < 4; ++n) acc[m][n] = zero4;
    {   // pipelined W-frags: kk+1 issued before kk's MFMAs (wc4 pre-loaded)
        bf16x8 wn_[4];
        #pragma unroll
        for (int kk = 0; kk < 8; ++kk) {
            if (kk < 7) {
                #pragma unroll
                for (int m = 0; m < 4; ++m)
                    wn_[m] = *reinterpret_cast<const bf16x8*>(
                        W2p + ((((kk + 1) * 16 + wn * 4 + m) << 6) + lane) * 8);
            }
            const int k = kk * 32 + lhi * 8;
            bf16x8 xf[4];
            #pragma unroll
            for (int n = 0; n < 4; ++n) {
                int r = n * 16 + l15;
                xf[n] = *reinterpret_cast<const bf16x8*>(
                    &hs[r * 512 + ((k * 2) ^ ((r & 15) << 4))]);
            }
            __builtin_amdgcn_s_setprio(1);
            #pragma unroll
            for (int m = 0; m < 4; ++m)
                #pragma unroll
                for (int n = 0; n < 4; ++n)
                    acc[m][n] = __builtin_amdgcn_mfma_f32_16x16x32_bf16(
                        wc4[m], xf[n], acc[m][n], 0, 0, 0);
            __builtin_amdgcn_s_setprio(0);
            #pragma unroll
            for (int m = 0; m < 4; ++m) wc4[m] = wn_[m];
        }
    }
    // W3 kk=0 warm-up (register-safe here)
    bf16x8 wc2[2];
    #pragma unroll
    for (int m = 0; m < 2; ++m)
        wc2[m] = *reinterpret_cast<const bf16x8*>(
            W3p + (((wn * 2 + m) << 6) + lane) * 8);
    // h2 epilogue -> hs2 (disjoint from hs): no pre-barrier needed.
    #pragma unroll
    for (int m = 0; m < 4; ++m) {
        int f = wn * 64 + m * 16 + lhi * 4;
        f32x4 bb = *reinterpret_cast<const f32x4*>(b2 + f);
        #pragma unroll
        for (int n = 0; n < 4; ++n) {
            int e = n * 16 + l15;
            f32x4 v = acc[m][n];
            u32x2 h;
            h.x = cvtpk(lrelu(v[0] + bb.x), lrelu(v[1] + bb.y));
            h.y = cvtpk(lrelu(v[2] + bb.z), lrelu(v[3] + bb.w));
            *reinterpret_cast<u32x2*>(
                &hs2[e * 512 + ((f * 2) ^ ((e & 15) << 4))]) = h;
        }
    }
    __syncthreads();   // barrier 2: h2 visible

    // ============================ layer 3 (K=256, N=128 feats) ==============
    f32x4 acc3[2][4];
    #pragma unroll
    for (int m = 0; m < 2; ++m)
        #pragma unroll
        for (int n = 0; n < 4; ++n) acc3[m][n] = zero4;
    {
        bf16x8 wn_[2];
        #pragma unroll
        for (int kk = 0; kk < 8; ++kk) {
            if (kk < 7) {
                #pragma unroll
                for (int m = 0; m < 2; ++m)
                    wn_[m] = *reinterpret_cast<const bf16x8*>(
                        W3p + ((((kk + 1) * 8 + wn * 2 + m) << 6) + lane) * 8);
            }
            const int k = kk * 32 + lhi * 8;
            bf16x8 xf[4];
            #pragma unroll
            for (int n = 0; n < 4; ++n) {
                int r = n * 16 + l15;
                xf[n] = *reinterpret_cast<const bf16x8*>(
                    &hs2[r * 512 + ((k * 2) ^ ((r & 15) << 4))]);
            }
            __builtin_amdgcn_s_setprio(1);
            #pragma unroll
            for (int m = 0; m < 2; ++m)
                #pragma unroll
                for (int n = 0; n < 4; ++n)
                    acc3[m][n] = __builtin_amdgcn_mfma_f32_16x16x32_bf16(
                        wc2[m], xf[n], acc3[m][n], 0, 0, 0);
            __builtin_amdgcn_s_setprio(0);
            #pragma unroll
            for (int m = 0; m < 2; ++m) wc2[m] = wn_[m];
        }
    }

    // ================= fused LayerNorm epilogue (h3 in registers) ===========
    #pragma unroll
    for (int m = 0; m < 2; ++m) {
        int f = wn * 32 + m * 16 + lhi * 4;
        f32x4 bb = *reinterpret_cast<const f32x4*>(b3 + f);
        #pragma unroll
        for (int n = 0; n < 4; ++n) {
            f32x4 v = acc3[m][n];
            v.x = lrelu(v.x + bb.x); v.y = lrelu(v.y + bb.y);
            v.z = lrelu(v.z + bb.z); v.w = lrelu(v.w + bb.w);
            acc3[m][n] = v;
        }
    }
    // per-edge partials over this wave's 32 feats: reduce across lhi (bits 4,5)
    #pragma unroll
    for (int n = 0; n < 4; ++n) {
        float s = 0.f, s2 = 0.f;
        #pragma unroll
        for (int m = 0; m < 2; ++m) {
            f32x4 v = acc3[m][n];
            s  += v.x + v.y + v.z + v.w;
            s2 += v.x * v.x + v.y * v.y + v.z * v.z + v.w * v.w;
        }
        s  += __shfl_xor(s, 16);  s  += __shfl_xor(s, 32);
        s2 += __shfl_xor(s2, 16); s2 += __shfl_xor(s2, 32);
        if (lhi == 0) {
            lnp[n * 16 + l15][wn][0] = s;
            lnp[n * 16 + l15][wn][1] = s2;
        }
    }
    __syncthreads();   // barrier 3: partials visible
    {
        const int f0 = wn * 32 + lhi * 4;
        const int f1 = f0 + 16;
        f32x4 gam0 = *reinterpret_cast<const f32x4*>(gamma + f0);
        f32x4 gam1 = *reinterpret_cast<const f32x4*>(gamma + f1);
        f32x4 bet0 = *reinterpret_cast<const f32x4*>(beta + f0);
        f32x4 bet1 = *reinterpret_cast<const f32x4*>(beta + f1);
        #pragma unroll
        for (int n = 0; n < 4; ++n) {
            int e = n * 16 + l15;
            f32x4 pa = *reinterpret_cast<const f32x4*>(&lnp[e][0][0]);
            f32x4 pb = *reinterpret_cast<const f32x4*>(&lnp[e][2][0]);
            float s    = pa.x + pa.z + pb.x + pb.z;
            float s2   = pa.y + pa.w + pb.y + pb.w;
            float mean = s * (1.f / 128.f);
            float var  = s2 * (1.f / 128.f) - mean * mean;
            float rstd = rsqrtf(var + 1e-5f);
            int rg = m0 + e;
            if (EXACT || rg < E) {
                float* op = out + (size_t)rg * 128;
                f32x4 v0 = acc3[0][n], v1 = acc3[1][n];
                f32x4 o0, o1;
                o0.x = (v0.x - mean) * rstd * gam0.x + bet0.x;
                o0.y = (v0.y - mean) * rstd * gam0.y + bet0.y;
                o0.z = (v0.z - mean) * rstd * gam0.z + bet0.z;
                o0.w = (v0.w - mean) * rstd * gam0.w + bet0.w;
                o1.x = (v1.x - mean) * rstd * gam1.x + bet1.x;
                o1.y = (v1.y - mean) * rstd * gam1.y + bet1.y;
                o1.z = (v1.z - mean) * rstd * gam1.z + bet1.z;
                o1.w = (v1.w - mean) * rstd * gam1.w + bet1.w;
                *reinterpret_cast<f32x4*>(op + f0) = o0;
                *reinterpret_cast<f32x4*>(op + f1) = o1;
            }
        }
    }
}

extern "C" void kernel_launch(void* const* d_in, const int* in_sizes, int n_in,
                              void* d_out, int out_size, void* d_ws, size_t ws_size,
                              hipStream_t stream) {
    const float* src  = (const float*)d_in[0];
    const float* dst  = (const float*)d_in[1];
    const float* ea   = (const float*)d_in[2];
    const float* u    = (const float*)d_in[3];
    const int*   bat  = (const int*)d_in[4];
    const float* W1   = (const float*)d_in[5];
    const float* b1   = (const float*)d_in[6];
    const float* W2   = (const float*)d_in[7];
    const float* b2   = (const float*)d_in[8];
    const float* W3   = (const float*)d_in[9];
    const float* b3   = (const float*)d_in[10];
    const float* gam  = (const float*)d_in[11];
    const float* bet  = (const float*)d_in[12];
    float* out = (float*)d_out;
    unsigned short* Wp = (unsigned short*)d_ws;   // 458752 B used

    const int E = in_sizes[0] / 128;

    prep_pack<<<896, 256, 0, stream>>>(W1, W2, W3, Wp);
    const int nblk = (E + 63) / 64;
    if ((E & 63) == 0)
        edge_mlp<true><<<nblk, 256, 0, stream>>>(src, dst, ea, u, bat, Wp,
                                                 b1, b2, b3, gam, bet, out, E);
    else
        edge_mlp<false><<<nblk, 256, 0, stream>>>(src, dst, ea, u, bat, Wp,
                                                  b1, b2, b3, gam, bet, out, E);
}

// Round 16
// 294.369 us; speedup vs baseline: 1.7066x; 1.7066x over previous
//
#include <hip/hip_runtime.h>

// ---------------------------------------------------------------------------
// EdgeModel: out = LayerNorm(LReLU(LReLU(LReLU(X@W1+b1)@W2+b2)@W3+b3))
// X = concat[src, dest, edge_attr, u[batch]]  (E=400000, 512 features)
// R16: RESTORE R13 (best-known robust state, ~294us; R10-equivalent within
//      noise). R15's barrier-free L1 refuted (-70%: uncoalesced 16-segment
//      loads + naked HBM latency beat the staging cost it removed).
//      Final structure: R8 depth-2 input prefetch + R9 operand swap
//      (D[feat][edge], vector epilogues, cvt_pk) + R10 fat K=128 phases /
//      buffer disjointness / setprio + R12 fused LN + W warm-ups + R13
//      4-bit XOR swizzle. acc[4][4] => 2 waves/SIMD (no cap: caps spill).
// ---------------------------------------------------------------------------

typedef short bf16x8 __attribute__((ext_vector_type(8)));   // 8 bf16 (guide §3)
typedef float f32x4 __attribute__((ext_vector_type(4)));
typedef unsigned int u32;
typedef unsigned int u32x2 __attribute__((ext_vector_type(2)));

__device__ __forceinline__ unsigned short f2bf(float f) {  // RNE f32->bf16
    union { float f; unsigned u; } v; v.f = f;
    return (unsigned short)((v.u + 0x7fffu + ((v.u >> 16) & 1u)) >> 16);
}
__device__ __forceinline__ u32 cvtpk(float lo, float hi) { // d={bf16(hi),bf16(lo)}
    u32 r;
    asm("v_cvt_pk_bf16_f32 %0, %1, %2" : "=v"(r) : "v"(lo), "v"(hi));
    return r;
}
__device__ __forceinline__ float lrelu(float v) { return v >= 0.f ? v : 0.01f * v; }

// ---------------------------------------------------------------------------
// Pack W (K x N, row-major f32) into bf16 MFMA fragment order (A operand):
// frag(fk,fn): lane l, elem j  ->  W[fk*32 + (l>>4)*8 + j][fn*16 + (l&15)]
// offset(elems) = ((fk*nfn + fn)*64 + l)*8 + j
// ---------------------------------------------------------------------------
__global__ void prep_pack(const float* __restrict__ W1, const float* __restrict__ W2,
                          const float* __restrict__ W3, unsigned short* __restrict__ P) {
    int idx = blockIdx.x * 256 + threadIdx.x;
    const float* W; int N, base;
    if (idx < 131072)      { W = W1; N = 256; base = 0; }
    else if (idx < 196608) { W = W2; N = 256; base = 131072; }
    else if (idx < 229376) { W = W3; N = 128; base = 196608; }
    else return;
    int t = idx - base;
    int j = t & 7, l = (t >> 3) & 63, f = t >> 9;
    int nfn = N >> 4;
    int fk = f / nfn, fn = f - fk * nfn;
    int k = fk * 32 + ((l >> 4) << 3) + j;
    int c = fn * 16 + (l & 15);
    P[idx] = f2bf(W[k * N + c]);
}

// ---------------------------------------------------------------------------
// Main fused kernel. Block = 256 threads (4 waves, feat-split), M_TILE = 64.
// Wave: 64 feats x 64 edges. acc[4][4] (feat-frag x edge-frag), D[feat][edge].
// LDS: xs 2x16KB (dbuf 64x128 bf16 K-slice; reused as h2 after L1)
//    + hs 32KB (h1 bf16) + lnp 2KB = 66KB -> 2 blocks/CU.
// ---------------------------------------------------------------------------
template <bool EXACT>
__global__ __launch_bounds__(256) void edge_mlp(
    const float* __restrict__ src, const float* __restrict__ dst,
    const float* __restrict__ ea,  const float* __restrict__ u,
    const int* __restrict__ batch, const unsigned short* __restrict__ Wp,
    const float* __restrict__ b1,  const float* __restrict__ b2,
    const float* __restrict__ b3,  const float* __restrict__ gamma,
    const float* __restrict__ beta, float* __restrict__ out, int E)
{
    __shared__ __align__(16) unsigned char xs[2][64 * 256];  // 2x16KB
    __shared__ __align__(16) unsigned char hs[64 * 512];     // 32KB (h1)
    __shared__ __align__(16) float lnp[64][4][2];            // 2KB partials

    const int tid  = threadIdx.x;
    const int lane = tid & 63;
    const int wn   = tid >> 6;          // wave 0..3 = feature quarter
    const int l15  = lane & 15;
    const int lhi  = lane >> 4;         // 0..3
    const int m0   = blockIdx.x * 64;
    const int ldr8 = tid >> 5;          // 0..7: staging row within 8-row group
    const int ldc5 = tid & 31;          // 0..31: f32x4 column in 128-col slice

    // Hoisted row indices + batch gather (one per 8-row group)
    int grow[8], gb[8];
    #pragma unroll
    for (int p = 0; p < 8; ++p) {
        int rg = m0 + p * 8 + ldr8;
        if (!EXACT) rg = rg < E ? rg : E - 1;
        grow[p] = rg;
        gb[p]   = batch[rg];
    }

    const unsigned short* W1p = Wp;
    const unsigned short* W2p = Wp + 131072;
    const unsigned short* W3p = Wp + 196608;

    const f32x4 zero4 = {0.f, 0.f, 0.f, 0.f};
    f32x4 acc[4][4];                    // [feat-frag][edge-frag]
    #pragma unroll
    for (int m = 0; m < 4; ++m)
        #pragma unroll
        for (int n = 0; n < 4; ++n) acc[m][n] = zero4;

    // Load one full 128-K segment (seg: 0:src 1:dst 2:ea 3:u[batch])
    auto L1LOAD = [&](f32x4 (&pf)[8], int seg) {
        #pragma unroll
        for (int p = 0; p < 8; ++p) {
            const float* gp;
            if (seg == 3) gp = u + (size_t)gb[p] * 128 + ldc5 * 4;
            else {
                const float* bp = (seg == 0) ? src : (seg == 1) ? dst : ea;
                gp = bp + (size_t)grow[p] * 128 + ldc5 * 4;
            }
            pf[p] = *reinterpret_cast<const f32x4*>(gp);
        }
    };
    auto L1WRITE = [&](unsigned char* buf, f32x4 (&pf)[8]) {
        #pragma unroll
        for (int p = 0; p < 8; ++p) {
            int r = p * 8 + ldr8;
            u32x2 h; h.x = cvtpk(pf[p].x, pf[p].y); h.y = cvtpk(pf[p].z, pf[p].w);
            *reinterpret_cast<u32x2*>(
                &buf[r * 256 + ((ldc5 * 8) ^ ((r & 15) << 4))]) = h;
        }
    };

    // ============================ layer 1 (K=512) ===========================
    // 4 phases of K=128; depth-2 input prefetch; per-half upfront W-frags.
    f32x4 pf0[8], pf1[8];
    L1LOAD(pf0, 0);
    L1WRITE(xs[0], pf0);
    L1LOAD(pf1, 1);
    __syncthreads();

    #pragma unroll
    for (int p = 0; p < 4; ++p) {
        const int c = p & 1;
        if (p + 2 < 4) { if (c == 0) L1LOAD(pf0, p + 2); else L1LOAD(pf1, p + 2); }
        if (p + 1 < 4) { if (c == 0) L1WRITE(xs[1], pf1); else L1WRITE(xs[0], pf0); }
        #pragma unroll
        for (int h = 0; h < 2; ++h) {   // two K=64 halves; W-frags 2 kk upfront
            bf16x8 wA[4], wB[4];
            const int fkA = p * 4 + h * 2, fkB = fkA + 1;
            #pragma unroll
            for (int m = 0; m < 4; ++m) {
                int fm = wn * 4 + m;
                wA[m] = *reinterpret_cast<const bf16x8*>(
                    W1p + (((fkA * 16 + fm) << 6) + lane) * 8);
                wB[m] = *reinterpret_cast<const bf16x8*>(
                    W1p + (((fkB * 16 + fm) << 6) + lane) * 8);
            }
            #pragma unroll
            for (int kk = 0; kk < 2; ++kk) {
                const int klo = (h * 2 + kk) * 32 + lhi * 8;
                bf16x8 xf[4];
                #pragma unroll
                for (int n = 0; n < 4; ++n) {
                    int r = n * 16 + l15;
                    xf[n] = *reinterpret_cast<const bf16x8*>(
                        &xs[c][r * 256 + ((klo * 2) ^ ((r & 15) << 4))]);
                }
                __builtin_amdgcn_s_setprio(1);
                #pragma unroll
                for (int m = 0; m < 4; ++m)
                    #pragma unroll
                    for (int n = 0; n < 4; ++n)
                        acc[m][n] = __builtin_amdgcn_mfma_f32_16x16x32_bf16(
                            kk == 0 ? wA[m] : wB[m], xf[n], acc[m][n], 0, 0, 0);
                __builtin_amdgcn_s_setprio(0);
            }
        }
        __syncthreads();
    }

    // W2 kk=0 warm-up: pf0/pf1 dead here -> register-safe; latency hides
    // under the h1 epilogue + barrier.
    bf16x8 wc4[4];
    #pragma unroll
    for (int m = 0; m < 4; ++m)
        wc4[m] = *reinterpret_cast<const bf16x8*>(
            W2p + (((wn * 4 + m) << 6) + lane) * 8);

    // h1 = LReLU(acc + b1) -> hs. Lane holds 4 consecutive feats of one edge.
    #pragma unroll
    for (int m = 0; m < 4; ++m) {
        int f = wn * 64 + m * 16 + lhi * 4;
        f32x4 bb = *reinterpret_cast<const f32x4*>(b1 + f);
        #pragma unroll
        for (int n = 0; n < 4; ++n) {
            int e = n * 16 + l15;
            f32x4 v = acc[m][n];
            u32x2 h;
            h.x = cvtpk(lrelu(v[0] + bb.x), lrelu(v[1] + bb.y));
            h.y = cvtpk(lrelu(v[2] + bb.z), lrelu(v[3] + bb.w));
            *reinterpret_cast<u32x2*>(
                &hs[e * 512 + ((f * 2) ^ ((e & 15) << 4))]) = h;
        }
    }
    __syncthreads();

    // ============================ layer 2 (K=256) ===========================
    // reads h1 (hs), writes h2 into the DEAD xs region (no overwrite barrier).
    unsigned char* h2s = xs[0];          // 32KB contiguous
    #pragma unroll
    for (int m = 0; m < 4; ++m)
        #pragma unroll
        for (int n = 0; n < 4; ++n) acc[m][n] = zero4;
    {   // pipelined W-frags: kk+1 issued before kk's MFMAs (wc4 pre-loaded)
        bf16x8 wn_[4];
        #pragma unroll
        for (int kk = 0; kk < 8; ++kk) {
            if (kk < 7) {
                #pragma unroll
                for (int m = 0; m < 4; ++m)
                    wn_[m] = *reinterpret_cast<const bf16x8*>(
                        W2p + ((((kk + 1) * 16 + wn * 4 + m) << 6) + lane) * 8);
            }
            const int k = kk * 32 + lhi * 8;
            bf16x8 xf[4];
            #pragma unroll
            for (int n = 0; n < 4; ++n) {
                int r = n * 16 + l15;
                xf[n] = *reinterpret_cast<const bf16x8*>(
                    &hs[r * 512 + ((k * 2) ^ ((r & 15) << 4))]);
            }
            __builtin_amdgcn_s_setprio(1);
            #pragma unroll
            for (int m = 0; m < 4; ++m)
                #pragma unroll
                for (int n = 0; n < 4; ++n)
                    acc[m][n] = __builtin_amdgcn_mfma_f32_16x16x32_bf16(
                        wc4[m], xf[n], acc[m][n], 0, 0, 0);
            __builtin_amdgcn_s_setprio(0);
            #pragma unroll
            for (int m = 0; m < 4; ++m) wc4[m] = wn_[m];
        }
    }
    // W3 kk=0 warm-up (register-safe here; hides under h2 epilogue + barrier)
    bf16x8 wc2[2];
    #pragma unroll
    for (int m = 0; m < 2; ++m)
        wc2[m] = *reinterpret_cast<const bf16x8*>(
            W3p + (((wn * 2 + m) << 6) + lane) * 8);
    // h2 epilogue -> h2s (disjoint from hs; xs dead): no pre-barrier needed.
    #pragma unroll
    for (int m = 0; m < 4; ++m) {
        int f = wn * 64 + m * 16 + lhi * 4;
        f32x4 bb = *reinterpret_cast<const f32x4*>(b2 + f);
        #pragma unroll
        for (int n = 0; n < 4; ++n) {
            int e = n * 16 + l15;
            f32x4 v = acc[m][n];
            u32x2 h;
            h.x = cvtpk(lrelu(v[0] + bb.x), lrelu(v[1] + bb.y));
            h.y = cvtpk(lrelu(v[2] + bb.z), lrelu(v[3] + bb.w));
            *reinterpret_cast<u32x2*>(
                &h2s[e * 512 + ((f * 2) ^ ((e & 15) << 4))]) = h;
        }
    }
    __syncthreads();   // h2 visible; also: all waves done READING h1 (hs)

    // ============================ layer 3 (K=256, N=128 feats) ==============
    f32x4 acc3[2][4];
    #pragma unroll
    for (int m = 0; m < 2; ++m)
        #pragma unroll
        for (int n = 0; n < 4; ++n) acc3[m][n] = zero4;
    {
        bf16x8 wn_[2];
        #pragma unroll
        for (int kk = 0; kk < 8; ++kk) {
            if (kk < 7) {
                #pragma unroll
                for (int m = 0; m < 2; ++m)
                    wn_[m] = *reinterpret_cast<const bf16x8*>(
                        W3p + ((((kk + 1) * 8 + wn * 2 + m) << 6) + lane) * 8);
            }
            const int k = kk * 32 + lhi * 8;
            bf16x8 xf[4];
            #pragma unroll
            for (int n = 0; n < 4; ++n) {
                int r = n * 16 + l15;
                xf[n] = *reinterpret_cast<const bf16x8*>(
                    &h2s[r * 512 + ((k * 2) ^ ((r & 15) << 4))]);
            }
            __builtin_amdgcn_s_setprio(1);
            #pragma unroll
            for (int m = 0; m < 2; ++m)
                #pragma unroll
                for (int n = 0; n < 4; ++n)
                    acc3[m][n] = __builtin_amdgcn_mfma_f32_16x16x32_bf16(
                        wc2[m], xf[n], acc3[m][n], 0, 0, 0);
            __builtin_amdgcn_s_setprio(0);
            #pragma unroll
            for (int m = 0; m < 2; ++m) wc2[m] = wn_[m];
        }
    }

    // ================= fused LayerNorm epilogue (h3 in registers) ===========
    #pragma unroll
    for (int m = 0; m < 2; ++m) {
        int f = wn * 32 + m * 16 + lhi * 4;
        f32x4 bb = *reinterpret_cast<const f32x4*>(b3 + f);
        #pragma unroll
        for (int n = 0; n < 4; ++n) {
            f32x4 v = acc3[m][n];
            v.x = lrelu(v.x + bb.x); v.y = lrelu(v.y + bb.y);
            v.z = lrelu(v.z + bb.z); v.w = lrelu(v.w + bb.w);
            acc3[m][n] = v;
        }
    }
    // per-edge partials over this wave's 32 feats: reduce across lhi (bits 4,5)
    #pragma unroll
    for (int n = 0; n < 4; ++n) {
        float s = 0.f, s2 = 0.f;
        #pragma unroll
        for (int m = 0; m < 2; ++m) {
            f32x4 v = acc3[m][n];
            s  += v.x + v.y + v.z + v.w;
            s2 += v.x * v.x + v.y * v.y + v.z * v.z + v.w * v.w;
        }
        s  += __shfl_xor(s, 16);  s  += __shfl_xor(s, 32);
        s2 += __shfl_xor(s2, 16); s2 += __shfl_xor(s2, 32);
        if (lhi == 0) {
            lnp[n * 16 + l15][wn][0] = s;
            lnp[n * 16 + l15][wn][1] = s2;
        }
    }
    __syncthreads();   // partials visible (h2s reads also complete)
    {
        const int f0 = wn * 32 + lhi * 4;
        const int f1 = f0 + 16;
        f32x4 gam0 = *reinterpret_cast<const f32x4*>(gamma + f0);
        f32x4 gam1 = *reinterpret_cast<const f32x4*>(gamma + f1);
        f32x4 bet0 = *reinterpret_cast<const f32x4*>(beta + f0);
        f32x4 bet1 = *reinterpret_cast<const f32x4*>(beta + f1);
        #pragma unroll
        for (int n = 0; n < 4; ++n) {
            int e = n * 16 + l15;
            f32x4 pa = *reinterpret_cast<const f32x4*>(&lnp[e][0][0]);
            f32x4 pb = *reinterpret_cast<const f32x4*>(&lnp[e][2][0]);
            float s    = pa.x + pa.z + pb.x + pb.z;
            float s2   = pa.y + pa.w + pb.y + pb.w;
            float mean = s * (1.f / 128.f);
            float var  = s2 * (1.f / 128.f) - mean * mean;
            float rstd = rsqrtf(var + 1e-5f);
            int rg = m0 + e;
            if (EXACT || rg < E) {
                float* op = out + (size_t)rg * 128;
                f32x4 v0 = acc3[0][n], v1 = acc3[1][n];
                f32x4 o0, o1;
                o0.x = (v0.x - mean) * rstd * gam0.x + bet0.x;
                o0.y = (v0.y - mean) * rstd * gam0.y + bet0.y;
                o0.z = (v0.z - mean) * rstd * gam0.z + bet0.z;
                o0.w = (v0.w - mean) * rstd * gam0.w + bet0.w;
                o1.x = (v1.x - mean) * rstd * gam1.x + bet1.x;
                o1.y = (v1.y - mean) * rstd * gam1.y + bet1.y;
                o1.z = (v1.z - mean) * rstd * gam1.z + bet1.z;
                o1.w = (v1.w - mean) * rstd * gam1.w + bet1.w;
                *reinterpret_cast<f32x4*>(op + f0) = o0;
                *reinterpret_cast<f32x4*>(op + f1) = o1;
            }
        }
    }
}

extern "C" void kernel_launch(void* const* d_in, const int* in_sizes, int n_in,
                              void* d_out, int out_size, void* d_ws, size_t ws_size,
                              hipStream_t stream) {
    const float* src  = (const float*)d_in[0];
    const float* dst  = (const float*)d_in[1];
    const float* ea   = (const float*)d_in[2];
    const float* u    = (const float*)d_in[3];
    const int*   bat  = (const int*)d_in[4];
    const float* W1   = (const float*)d_in[5];
    const float* b1   = (const float*)d_in[6];
    const float* W2   = (const float*)d_in[7];
    const float* b2   = (const float*)d_in[8];
    const float* W3   = (const float*)d_in[9];
    const float* b3   = (const float*)d_in[10];
    const float* gam  = (const float*)d_in[11];
    const float* bet  = (const float*)d_in[12];
    float* out = (float*)d_out;
    unsigned short* Wp = (unsigned short*)d_ws;   // 458752 B used

    const int E = in_sizes[0] / 128;

    prep_pack<<<896, 256, 0, stream>>>(W1, W2, W3, Wp);
    const int nblk = (E + 63) / 64;
    if ((E & 63) == 0)
        edge_mlp<true><<<nblk, 256, 0, stream>>>(src, dst, ea, u, bat, Wp,
                                                 b1, b2, b3, gam, bet, out, E);
    else
        edge_mlp<false><<<nblk, 256, 0, stream>>>(src, dst, ea, u, bat, Wp,
                                                  b1, b2, b3, gam, bet, out, E);
}